// Round 5
// baseline (147.439 us; speedup 1.0000x reference)
//
#include <hip/hip_runtime.h>
#include <math.h>

// B=64, T=512, C=384, H=64. fp32 in/out; bf16 MFMA internally.
#define NB 64
#define NT 512
#define NC 384
#define NH 64

typedef __attribute__((ext_vector_type(8))) short bf16x8;
typedef __attribute__((ext_vector_type(4))) float f32x4;

__device__ __forceinline__ unsigned short f2bf(float f) {
  unsigned int u = __float_as_uint(f);
  return (unsigned short)((u + 0x7FFFu + ((u >> 16) & 1u)) >> 16);
}
__device__ __forceinline__ unsigned int pk2bf(float a, float b) {
  return (unsigned int)f2bf(a) | ((unsigned int)f2bf(b) << 16);
}

// ---------------------------------------------------------------------------
// Kernel 0: W[384][64] fp32 x3 -> Wt[192][384] bf16 (transposed, row-major)
// ---------------------------------------------------------------------------
__global__ __launch_bounds__(256) void wtrans_kernel(
    const float* __restrict__ Wq, const float* __restrict__ Wk,
    const float* __restrict__ Wv, unsigned short* __restrict__ Wt) {
  int id = blockIdx.x * 256 + threadIdx.x;
  if (id >= 3 * NC * NH) return;
  int m = id / (NC * NH);
  int r = id % (NC * NH);
  int c = r / NH;
  int h = r % NH;
  const float* W = (m == 0) ? Wq : ((m == 1) ? Wk : Wv);
  Wt[(m * NH + h) * NC + c] = f2bf(W[c * NH + h]);
}

// ---------------------------------------------------------------------------
// Kernel 1: fused QKV projection. M=32768, K=384, N=192.
// x tile staged to LDS ONCE (coalesced, 1 barrier). Wt B-frags register
// double-buffered, prefetched one 32-K chunk ahead -> zero K-loop barriers.
// q scaled by 0.125 (exact). V transposed via LDS -> coalesced vt[b][h][t].
// ---------------------------------------------------------------------------
#define XS 392
__global__ __launch_bounds__(256) void proj_kernel(
    const float* __restrict__ x, const unsigned short* __restrict__ Wt,
    unsigned short* __restrict__ q, unsigned short* __restrict__ k,
    unsigned short* __restrict__ vt) {
  __shared__ unsigned short xs[64 * XS];  // 50176 B
  const int t = threadIdx.x;
  const int m0 = blockIdx.x * 64;
  const int w = t >> 6, l = t & 63, mi = l & 15, quad = l >> 4;

  // lane's B-frag base: row (nt*16+mi), col quad*8
  const unsigned short* wp = Wt + (size_t)mi * NC + quad * 8;

  bf16x8 b0[12], b1[12];
  // preload chunk 0 (latency hides under x staging)
#pragma unroll
  for (int nt = 0; nt < 12; ++nt)
    b0[nt] = *(const bf16x8*)(wp + (size_t)nt * 16 * NC);

  // stage x tile: 64 rows x 384 fp32 -> bf16 (coalesced)
  for (int i = 0; i < 24; ++i) {
    int u = t + i * 256;
    int row = u / 96;
    int cp = (u % 96) * 4;
    float4 a = *(const float4*)(x + (size_t)(m0 + row) * NC + cp);
    ushort4 bb;
    bb.x = f2bf(a.x); bb.y = f2bf(a.y); bb.z = f2bf(a.z); bb.w = f2bf(a.w);
    *(ushort4*)&xs[row * XS + cp] = bb;
  }
  __syncthreads();

  f32x4 acc[12];
  const f32x4 zero = {0.f, 0.f, 0.f, 0.f};
#pragma unroll
  for (int i = 0; i < 12; ++i) acc[i] = zero;

  const unsigned short* arow = &xs[(w * 16 + mi) * XS + quad * 8];

#pragma unroll
  for (int kc2 = 0; kc2 < 6; ++kc2) {
    const int kcA = kc2 * 2, kcB = kc2 * 2 + 1;
    // prefetch chunk kcB into b1 (independent of b0 MFMAs below)
#pragma unroll
    for (int nt = 0; nt < 12; ++nt)
      b1[nt] = *(const bf16x8*)(wp + (size_t)nt * 16 * NC + kcB * 32);
    bf16x8 a = *(const bf16x8*)(arow + kcA * 32);
#pragma unroll
    for (int nt = 0; nt < 12; ++nt)
      acc[nt] = __builtin_amdgcn_mfma_f32_16x16x32_bf16(a, b0[nt], acc[nt], 0, 0, 0);
    // prefetch chunk kcA+2 into b0
    if (kc2 < 5) {
#pragma unroll
      for (int nt = 0; nt < 12; ++nt)
        b0[nt] = *(const bf16x8*)(wp + (size_t)nt * 16 * NC + (kcA + 2) * 32);
    }
    a = *(const bf16x8*)(arow + kcB * 32);
#pragma unroll
    for (int nt = 0; nt < 12; ++nt)
      acc[nt] = __builtin_amdgcn_mfma_f32_16x16x32_bf16(a, b1[nt], acc[nt], 0, 0, 0);
  }

  // epilogue. C/D layout: col=lane&15 (=n), row=quad*4+r
  const int rbase = m0 + w * 16 + quad * 4;
#pragma unroll
  for (int nt = 0; nt < 4; ++nt)  // q, fold 1/sqrt(64)=0.125 (exact)
#pragma unroll
    for (int r = 0; r < 4; ++r)
      q[(size_t)(rbase + r) * NH + nt * 16 + mi] = f2bf(acc[nt][r] * 0.125f);
#pragma unroll
  for (int nt = 4; nt < 8; ++nt)  // k
#pragma unroll
    for (int r = 0; r < 4; ++r)
      k[(size_t)(rbase + r) * NH + (nt - 4) * 16 + mi] = f2bf(acc[nt][r]);

  // v: transpose via LDS (reuse xs), then coalesced store to vt[b][h][t]
  __syncthreads();  // all xs A-frag reads complete
#pragma unroll
  for (int nt = 8; nt < 12; ++nt) {
    int h = (nt - 8) * 16 + mi;
#pragma unroll
    for (int r = 0; r < 4; ++r)
      xs[h * 72 + w * 16 + quad * 4 + r] = f2bf(acc[nt][r]);
  }
  __syncthreads();
  {
    int bb = m0 >> 9, t0 = m0 & 511;
#pragma unroll
    for (int i = 0; i < 2; ++i) {
      int u = t + i * 256;  // 512 uint4 units: 64 h x 8 segs
      int h = u >> 3, seg = u & 7;
      *(uint4*)&vt[((size_t)bb * NH + h) * NT + t0 + seg * 8] =
          *(const uint4*)&xs[h * 72 + seg * 8];
    }
  }
}

// ---------------------------------------------------------------------------
// Kernel 2: causal flash attention. ONE WAVE per (b, 16-row q-tile).
// K/V fragments register double-buffered: tile kt+1's 16 loads issued while
// tile kt computes (S-MFMA -> softmax -> LDS-P roundtrip -> PV). Zero
// barriers. Grid 2048; heavy q-tiles dispatched first.
// ---------------------------------------------------------------------------
#define PSTR 72

#define LOADKV(KA0, KA1, VA0, VA1, kt_)                                   \
  do {                                                                    \
    const unsigned short* kb_ = k + ((size_t)b * NT + (kt_) * 64) * NH;   \
    const unsigned short* vb_ = vt + (size_t)b * NH * NT + (kt_) * 64;    \
    _Pragma("unroll") for (int nt = 0; nt < 4; ++nt) {                    \
      const unsigned short* kr = kb_ + (size_t)(nt * 16 + mi) * NH + quad * 8; \
      KA0[nt] = *(const bf16x8*)kr;                                       \
      KA1[nt] = *(const bf16x8*)(kr + 32);                                \
      const unsigned short* vr = vb_ + (size_t)(nt * 16 + mi) * NT + quad * 8; \
      VA0[nt] = *(const bf16x8*)vr;                                       \
      VA1[nt] = *(const bf16x8*)(vr + 32);                                \
    }                                                                     \
  } while (0)

#define PROCESS(KA0, KA1, VA0, VA1, kt_)                                  \
  do {                                                                    \
    float p[4][4];                                                        \
    _Pragma("unroll") for (int nt = 0; nt < 4; ++nt) {                    \
      f32x4 z = zero;                                                     \
      z = __builtin_amdgcn_mfma_f32_16x16x32_bf16(KA0[nt], qb0, z, 0, 0, 0); \
      z = __builtin_amdgcn_mfma_f32_16x16x32_bf16(KA1[nt], qb1, z, 0, 0, 0); \
      _Pragma("unroll") for (int r = 0; r < 4; ++r) p[nt][r] = z[r];      \
    }                                                                     \
    if ((kt_) == ktmax) {                                                 \
      _Pragma("unroll") for (int nt = 0; nt < 4; ++nt)                    \
        _Pragma("unroll") for (int r = 0; r < 4; ++r)                     \
          if ((kt_) * 64 + nt * 16 + quad * 4 + r > qi * 16 + mi)         \
            p[nt][r] = -INFINITY;                                         \
    }                                                                     \
    float vmax = -INFINITY;                                               \
    _Pragma("unroll") for (int nt = 0; nt < 4; ++nt)                      \
      _Pragma("unroll") for (int r = 0; r < 4; ++r)                       \
        vmax = fmaxf(vmax, p[nt][r]);                                     \
    vmax = fmaxf(vmax, __shfl_xor(vmax, 16));                             \
    vmax = fmaxf(vmax, __shfl_xor(vmax, 32));                             \
    float mn = fmaxf(mrow, vmax);                                         \
    float alpha = __expf(mrow - mn);                                      \
    mrow = mn;                                                            \
    float rsum = 0.f;                                                     \
    _Pragma("unroll") for (int nt = 0; nt < 4; ++nt)                      \
      _Pragma("unroll") for (int r = 0; r < 4; ++r) {                     \
        p[nt][r] = __expf(p[nt][r] - mn);                                 \
        rsum += p[nt][r];                                                 \
      }                                                                   \
    rsum += __shfl_xor(rsum, 16);                                         \
    rsum += __shfl_xor(rsum, 32);                                         \
    lrow = lrow * alpha + rsum;                                           \
    _Pragma("unroll") for (int nt = 0; nt < 4; ++nt) {                    \
      uint2 pk;                                                           \
      pk.x = pk2bf(p[nt][0], p[nt][1]);                                   \
      pk.y = pk2bf(p[nt][2], p[nt][3]);                                   \
      *(uint2*)&ps[mi * PSTR + nt * 16 + quad * 4] = pk;                  \
    }                                                                     \
    bf16x8 pa0 = *(const bf16x8*)&ps[mi * PSTR + quad * 8];               \
    bf16x8 pa1 = *(const bf16x8*)&ps[mi * PSTR + 32 + quad * 8];          \
    float av[4];                                                          \
    _Pragma("unroll") for (int r = 0; r < 4; ++r)                         \
      av[r] = __shfl(alpha, quad * 4 + r);                                \
    _Pragma("unroll") for (int hi = 0; hi < 4; ++hi)                      \
      _Pragma("unroll") for (int r = 0; r < 4; ++r)                       \
        accO[hi][r] *= av[r];                                             \
    _Pragma("unroll") for (int hi = 0; hi < 4; ++hi) {                    \
      accO[hi] = __builtin_amdgcn_mfma_f32_16x16x32_bf16(pa0, VA0[hi], accO[hi], 0, 0, 0); \
      accO[hi] = __builtin_amdgcn_mfma_f32_16x16x32_bf16(pa1, VA1[hi], accO[hi], 0, 0, 0); \
    }                                                                     \
  } while (0)

__global__ __launch_bounds__(64) void attn_kernel(
    const unsigned short* __restrict__ q, const unsigned short* __restrict__ k,
    const unsigned short* __restrict__ vt, float* __restrict__ out) {
  __shared__ unsigned short ps[16 * PSTR];
  const int l = threadIdx.x;
  const int mi = l & 15, quad = l >> 4;
  const int bx = blockIdx.x;
  const int qi = 31 - (bx >> 6);  // heavy tiles first
  const int b = bx & 63;

  const unsigned short* qrow = q + ((size_t)b * NT + qi * 16 + mi) * NH;
  bf16x8 qb0 = *(const bf16x8*)(qrow + quad * 8);
  bf16x8 qb1 = *(const bf16x8*)(qrow + 32 + quad * 8);

  f32x4 accO[4];
  const f32x4 zero = {0.f, 0.f, 0.f, 0.f};
#pragma unroll
  for (int i = 0; i < 4; ++i) accO[i] = zero;
  float mrow = -INFINITY, lrow = 0.f;  // per-lane q-row = qi*16 + mi

  const int ktmax = (qi * 16 + 15) >> 6;

  bf16x8 k0a[4], k0b[4], v0a[4], v0b[4];
  bf16x8 k1a[4], k1b[4], v1a[4], v1b[4];
  LOADKV(k0a, k0b, v0a, v0b, 0);

  int kt = 0;
  while (true) {
    if (kt + 1 <= ktmax) LOADKV(k1a, k1b, v1a, v1b, kt + 1);
    PROCESS(k0a, k0b, v0a, v0b, kt);
    if (++kt > ktmax) break;
    if (kt + 1 <= ktmax) LOADKV(k0a, k0b, v0a, v0b, kt + 1);
    PROCESS(k1a, k1b, v1a, v1b, kt);
    if (++kt > ktmax) break;
  }

  // epilogue
  float inv = 1.f / lrow;
  const size_t obase = ((size_t)b * NT + qi * 16) * NH;
#pragma unroll
  for (int r = 0; r < 4; ++r) {
    float iv = __shfl(inv, quad * 4 + r);
#pragma unroll
    for (int hi = 0; hi < 4; ++hi)
      out[obase + (size_t)(quad * 4 + r) * NH + hi * 16 + mi] = accO[hi][r] * iv;
  }
}

extern "C" void kernel_launch(void* const* d_in, const int* in_sizes, int n_in,
                              void* d_out, int out_size, void* d_ws, size_t ws_size,
                              hipStream_t stream) {
  const float* x  = (const float*)d_in[0];
  const float* Wq = (const float*)d_in[1];
  const float* Wk = (const float*)d_in[2];
  const float* Wv = (const float*)d_in[3];

  unsigned short* Wt = (unsigned short*)d_ws;          // 192*384
  unsigned short* qb = Wt + 192 * 384;                 // 32768*64 each
  unsigned short* kb = qb + 32768 * 64;
  unsigned short* vtb = kb + 32768 * 64;               // Vt[b][h][t]
  float* out = (float*)d_out;

  wtrans_kernel<<<288, 256, 0, stream>>>(Wq, Wk, Wv, Wt);
  proj_kernel<<<512, 256, 0, stream>>>(x, Wt, qb, kb, vtb);
  attn_kernel<<<2048, 64, 0, stream>>>(qb, kb, vtb, out);
}

// Round 7
// 121.890 us; speedup vs baseline: 1.2096x; 1.2096x over previous
//
#include <hip/hip_runtime.h>
#include <math.h>

// B=64, T=512, C=384, H=64. fp32 in/out; bf16 MFMA internally.
#define NB 64
#define NT 512
#define NC 384
#define NH 64

typedef __attribute__((ext_vector_type(8))) short bf16x8;
typedef __attribute__((ext_vector_type(4))) float f32x4;

__device__ __forceinline__ unsigned short f2bf(float f) {
  unsigned int u = __float_as_uint(f);
  return (unsigned short)((u + 0x7FFFu + ((u >> 16) & 1u)) >> 16);
}
__device__ __forceinline__ unsigned int pk2bf(float a, float b) {
  return (unsigned int)f2bf(a) | ((unsigned int)f2bf(b) << 16);
}

// ---------------------------------------------------------------------------
// Kernel 0: W[384][64] fp32 x3 -> Wt[192][384] bf16 (transposed, row-major)
// ---------------------------------------------------------------------------
__global__ __launch_bounds__(256) void wtrans_kernel(
    const float* __restrict__ Wq, const float* __restrict__ Wk,
    const float* __restrict__ Wv, unsigned short* __restrict__ Wt) {
  int id = blockIdx.x * 256 + threadIdx.x;
  if (id >= 3 * NC * NH) return;
  int m = id / (NC * NH);
  int r = id % (NC * NH);
  int c = r / NH;
  int h = r % NH;
  const float* W = (m == 0) ? Wq : ((m == 1) ? Wk : Wv);
  Wt[(m * NH + h) * NC + c] = f2bf(W[c * NH + h]);
}

// ---------------------------------------------------------------------------
// Kernel 1: fused QKV projection. M=32768, K=384, N=192.
// 384 threads = 6 waves; wave w owns N-tiles {2w, 2w+1} (w0-1: q, w2-3: k,
// w4-5: v). Its 24 B-frags (96 VGPR) load from L2 once, latency hidden by
// the single staging barrier. K-loop = LDS A-frag reads + MFMA only.
// ONE barrier total; no LDS reuse; V stored directly from C-layout as
// contiguous ushort4 (4 tokens) into vt[b][h][t]. q scaled by 0.125 (exact).
// ---------------------------------------------------------------------------
#define XS 392  // 64 rows x 392 ushorts; 784 B row stride
__global__ __launch_bounds__(384, 3) void proj_kernel(
    const float* __restrict__ x, const unsigned short* __restrict__ Wt,
    unsigned short* __restrict__ q, unsigned short* __restrict__ k,
    unsigned short* __restrict__ vt) {
  __shared__ unsigned short xs[64 * XS];  // 50176 B
  const int t = threadIdx.x;  // 0..383
  const int m0 = blockIdx.x * 64;
  const int w = t / 64, l = t & 63, mi = l & 15, quad = l >> 4;

  // stage x tile: 64 rows x 384 fp32 -> bf16 (coalesced float4)
#pragma unroll 4
  for (int i = 0; i < 16; ++i) {
    int u = t + i * 384;  // 0..6143; row = u/96, 4-float seg = u%96
    int row = u / 96;
    int cp = (u % 96) * 4;
    float4 a = *(const float4*)(x + (size_t)(m0 + row) * NC + cp);
    ushort4 bb;
    bb.x = f2bf(a.x); bb.y = f2bf(a.y); bb.z = f2bf(a.z); bb.w = f2bf(a.w);
    *(ushort4*)&xs[row * XS + cp] = bb;
  }

  // wave-resident B-frags: tiles 2w, 2w+1 (issued before the barrier so L2
  // latency overlaps other waves' staging)
  bf16x8 bfr[2][12];
#pragma unroll
  for (int ntl = 0; ntl < 2; ++ntl) {
    const unsigned short* wr =
        Wt + (size_t)((w * 2 + ntl) * 16 + mi) * NC + quad * 8;
#pragma unroll
    for (int kc = 0; kc < 12; ++kc)
      bfr[ntl][kc] = *(const bf16x8*)(wr + kc * 32);
  }
  __syncthreads();

  f32x4 acc[2][4];  // [ntl][msub]
  const f32x4 zero = {0.f, 0.f, 0.f, 0.f};
#pragma unroll
  for (int i = 0; i < 2; ++i)
#pragma unroll
    for (int j = 0; j < 4; ++j) acc[i][j] = zero;

#pragma unroll
  for (int msub = 0; msub < 4; ++msub) {
#pragma unroll
    for (int kc = 0; kc < 12; ++kc) {
      bf16x8 a = *(const bf16x8*)&xs[(msub * 16 + mi) * XS + kc * 32 + quad * 8];
      acc[0][msub] =
          __builtin_amdgcn_mfma_f32_16x16x32_bf16(a, bfr[0][kc], acc[0][msub], 0, 0, 0);
      acc[1][msub] =
          __builtin_amdgcn_mfma_f32_16x16x32_bf16(a, bfr[1][kc], acc[1][msub], 0, 0, 0);
    }
  }

  // epilogue (no barriers, pure global stores).
  // C/D layout: col=mi (=n within tile), row=quad*4+r (=m). Tile = 2w+ntl;
  // matrix = tile>>2 (uniform per wave), h = (tile&3)*16 + mi.
  if (w < 4) {  // q (waves 0-1) / k (waves 2-3): scalar ushort stores
    unsigned short* dst = (w < 2) ? q : k;
    const float sc = (w < 2) ? 0.125f : 1.0f;  // fold 1/sqrt(64), exact
#pragma unroll
    for (int ntl = 0; ntl < 2; ++ntl) {
      int tile = w * 2 + ntl;
      int h = (tile & 3) * 16 + mi;
#pragma unroll
      for (int msub = 0; msub < 4; ++msub)
#pragma unroll
        for (int r = 0; r < 4; ++r)
          dst[(size_t)(m0 + msub * 16 + quad * 4 + r) * NH + h] =
              f2bf(acc[ntl][msub][r] * sc);
    }
  } else {  // v (waves 4-5): 4 consecutive tokens per lane -> ushort4 store
    int bb = m0 >> 9, t0 = m0 & 511;
#pragma unroll
    for (int ntl = 0; ntl < 2; ++ntl) {
      int tile = w * 2 + ntl;
      int h = (tile & 3) * 16 + mi;
#pragma unroll
      for (int msub = 0; msub < 4; ++msub) {
        ushort4 s;
        s.x = f2bf(acc[ntl][msub][0]);
        s.y = f2bf(acc[ntl][msub][1]);
        s.z = f2bf(acc[ntl][msub][2]);
        s.w = f2bf(acc[ntl][msub][3]);
        *(ushort4*)&vt[((size_t)bb * NH + h) * NT + t0 + msub * 16 + quad * 4] = s;
      }
    }
  }
}

// ---------------------------------------------------------------------------
// Kernel 2: causal flash attention (r4 form, passed twice). ONE WAVE per
// (b, 16-row q-tile). Fragments gathered from L2-hot global, 16 loads in
// flight per k-tile; P round-trip via wave-local LDS; zero barriers.
// ---------------------------------------------------------------------------
#define PSTR 72
__global__ __launch_bounds__(64) void attn_kernel(
    const unsigned short* __restrict__ q, const unsigned short* __restrict__ k,
    const unsigned short* __restrict__ vt, float* __restrict__ out) {
  __shared__ unsigned short ps[16 * PSTR];
  const int l = threadIdx.x;
  const int mi = l & 15, quad = l >> 4;
  const int bx = blockIdx.x;
  const int qi = 31 - (bx >> 6);  // heavy tiles first
  const int b = bx & 63;

  const unsigned short* qrow = q + ((size_t)b * NT + qi * 16 + mi) * NH;
  bf16x8 qb0 = *(const bf16x8*)(qrow + quad * 8);
  bf16x8 qb1 = *(const bf16x8*)(qrow + 32 + quad * 8);

  f32x4 accO[4];
  const f32x4 zero = {0.f, 0.f, 0.f, 0.f};
#pragma unroll
  for (int i = 0; i < 4; ++i) accO[i] = zero;
  float mrow = -INFINITY, lrow = 0.f;  // per-lane q-row = qi*16 + mi

  const int ktmax = (qi * 16 + 15) >> 6;
  for (int kt = 0; kt <= ktmax; ++kt) {
    const unsigned short* kb = k + ((size_t)b * NT + kt * 64) * NH;
    const unsigned short* vb = vt + (size_t)b * NH * NT + kt * 64;
    bf16x8 ka0[4], ka1[4], va0[4], va1[4];
#pragma unroll
    for (int nt = 0; nt < 4; ++nt) {
      const unsigned short* kr = kb + (size_t)(nt * 16 + mi) * NH + quad * 8;
      ka0[nt] = *(const bf16x8*)kr;
      ka1[nt] = *(const bf16x8*)(kr + 32);
      const unsigned short* vr = vb + (size_t)(nt * 16 + mi) * NT + quad * 8;
      va0[nt] = *(const bf16x8*)vr;
      va1[nt] = *(const bf16x8*)(vr + 32);
    }

    // S^T tile: A = K rows (m=key), B = Q rows (n=q).
    float p[4][4];
#pragma unroll
    for (int nt = 0; nt < 4; ++nt) {
      f32x4 z = zero;
      z = __builtin_amdgcn_mfma_f32_16x16x32_bf16(ka0[nt], qb0, z, 0, 0, 0);
      z = __builtin_amdgcn_mfma_f32_16x16x32_bf16(ka1[nt], qb1, z, 0, 0, 0);
#pragma unroll
      for (int r = 0; r < 4; ++r) p[nt][r] = z[r];
    }

    if (kt == ktmax) {  // causal mask on diagonal tile
#pragma unroll
      for (int nt = 0; nt < 4; ++nt)
#pragma unroll
        for (int r = 0; r < 4; ++r)
          if (kt * 64 + nt * 16 + quad * 4 + r > qi * 16 + mi)
            p[nt][r] = -INFINITY;
    }

    // online softmax for q=mi (keys spread across quads)
    float vmax = -INFINITY;
#pragma unroll
    for (int nt = 0; nt < 4; ++nt)
#pragma unroll
      for (int r = 0; r < 4; ++r) vmax = fmaxf(vmax, p[nt][r]);
    vmax = fmaxf(vmax, __shfl_xor(vmax, 16));
    vmax = fmaxf(vmax, __shfl_xor(vmax, 32));
    float mn = fmaxf(mrow, vmax);
    float alpha = __expf(mrow - mn);
    mrow = mn;

    float rsum = 0.f;
#pragma unroll
    for (int nt = 0; nt < 4; ++nt)
#pragma unroll
      for (int r = 0; r < 4; ++r) {
        p[nt][r] = __expf(p[nt][r] - mn);
        rsum += p[nt][r];
      }
    rsum += __shfl_xor(rsum, 16);
    rsum += __shfl_xor(rsum, 32);
    lrow = lrow * alpha + rsum;

    // P -> LDS (row-contiguous, wave-local, no barrier) -> A-frags
#pragma unroll
    for (int nt = 0; nt < 4; ++nt) {
      uint2 pk;
      pk.x = pk2bf(p[nt][0], p[nt][1]);
      pk.y = pk2bf(p[nt][2], p[nt][3]);
      *(uint2*)&ps[mi * PSTR + nt * 16 + quad * 4] = pk;
    }
    bf16x8 pa0 = *(const bf16x8*)&ps[mi * PSTR + quad * 8];
    bf16x8 pa1 = *(const bf16x8*)&ps[mi * PSTR + 32 + quad * 8];

    float av[4];
#pragma unroll
    for (int r = 0; r < 4; ++r) av[r] = __shfl(alpha, quad * 4 + r);
#pragma unroll
    for (int hi = 0; hi < 4; ++hi)
#pragma unroll
      for (int r = 0; r < 4; ++r) accO[hi][r] *= av[r];

    // O += P V  (A = P rows, B = V^T rows; D col=h, row=q)
#pragma unroll
    for (int hi = 0; hi < 4; ++hi) {
      accO[hi] = __builtin_amdgcn_mfma_f32_16x16x32_bf16(pa0, va0[hi], accO[hi], 0, 0, 0);
      accO[hi] = __builtin_amdgcn_mfma_f32_16x16x32_bf16(pa1, va1[hi], accO[hi], 0, 0, 0);
    }
  }

  // epilogue
  float inv = 1.f / lrow;
  const size_t obase = ((size_t)b * NT + qi * 16) * NH;
#pragma unroll
  for (int r = 0; r < 4; ++r) {
    float iv = __shfl(inv, quad * 4 + r);
#pragma unroll
    for (int hi = 0; hi < 4; ++hi)
      out[obase + (size_t)(quad * 4 + r) * NH + hi * 16 + mi] = accO[hi][r] * iv;
  }
}

extern "C" void kernel_launch(void* const* d_in, const int* in_sizes, int n_in,
                              void* d_out, int out_size, void* d_ws, size_t ws_size,
                              hipStream_t stream) {
  const float* x  = (const float*)d_in[0];
  const float* Wq = (const float*)d_in[1];
  const float* Wk = (const float*)d_in[2];
  const float* Wv = (const float*)d_in[3];

  unsigned short* Wt = (unsigned short*)d_ws;          // 192*384
  unsigned short* qb = Wt + 192 * 384;                 // 32768*64 each
  unsigned short* kb = qb + 32768 * 64;
  unsigned short* vtb = kb + 32768 * 64;               // Vt[b][h][t]
  float* out = (float*)d_out;

  wtrans_kernel<<<288, 256, 0, stream>>>(Wq, Wk, Wv, Wt);
  proj_kernel<<<512, 384, 0, stream>>>(x, Wt, qb, kb, vtb);
  attn_kernel<<<2048, 64, 0, stream>>>(qb, kb, vtb, out);
}